// Round 9
// baseline (390.025 us; speedup 1.0000x reference)
//
#include <hip/hip_runtime.h>
#include <hip/hip_bf16.h>

typedef short bf8 __attribute__((ext_vector_type(8)));   // 8 bf16 (4 VGPRs)
typedef float f4 __attribute__((ext_vector_type(4)));
typedef const __attribute__((address_space(1))) void* gvp;
typedef __attribute__((address_space(3))) void* lvp;

#define S_LEN 4096
#define H_DIM 1024
#define D_DIM 512
#define B_DIM 16
#define OUT_BASE ((size_t)B_DIM * S_LEN * H_DIM)

// float -> bf16 bits, round-to-nearest-even
static __device__ __forceinline__ unsigned short f2bf(float f) {
    union { float f; unsigned int u; } c; c.f = f;
    unsigned int u = c.u;
    return (unsigned short)((u + 0x7FFFu + ((u >> 16) & 1u)) >> 16);
}

// cW1 [K=1024][N=512] f32 -> wT[n][chunk 0..31][slot 0..3] bf16 (pitch 2048 B),
// PRE-SWIZZLED: slot sl holds k-slot j = sl ^ ((n>>1)&3). GEMM's linear global_load_lds
// then swizzled ds_read (slot = lg ^ ((row>>1)&3)) recovers k-slot lg, 2-way-bank-free.
__global__ __launch_bounds__(256) void prep_transpose(const float* __restrict__ cW1,
                                                      unsigned short* __restrict__ wT) {
    __shared__ float tile[64][68];
    const int kt = blockIdx.x >> 3;   // 16 tiles of 64 k
    const int nt = blockIdx.x & 7;    // 8 tiles of 64 n
    const int tr = threadIdx.x >> 4;
    const int tc = threadIdx.x & 15;
#pragma unroll
    for (int i = 0; i < 4; ++i) {
        const f4 v = *(const f4*)(cW1 + (size_t)(kt * 64 + i * 16 + tr) * D_DIM + nt * 64 + tc * 4);
        tile[i * 16 + tr][tc * 4 + 0] = v.x;
        tile[i * 16 + tr][tc * 4 + 1] = v.y;
        tile[i * 16 + tr][tc * 4 + 2] = v.z;
        tile[i * 16 + tr][tc * 4 + 3] = v.w;
    }
    __syncthreads();
    const int n_local = threadIdx.x & 63;
    const int q = threadIdx.x >> 6;        // slot 0..3
    const int n = nt * 64 + n_local;
    const int j = q ^ ((n >> 1) & 3);      // data k-slot stored at slot q
    char* wTb = (char*)wT;
#pragma unroll
    for (int c_local = 0; c_local < 2; ++c_local) {   // two 32-k chunks per 64k tile
        const int k0 = c_local * 32 + j * 8;
        bf8 pk;
#pragma unroll
        for (int i = 0; i < 8; ++i) pk[i] = (short)f2bf(tile[k0 + i][n_local]);
        *(bf8*)(wTb + (size_t)n * 2048 + (kt * 2 + c_local) * 64 + q * 16) = pk;
    }
}

// Fused stream+GEMM. Block = one b x 32 consecutive s, N=512, BK=32 (32 chunks).
// 8 waves (2M x 4N), wave tile 16x128, acc[8] = 32 AGPR. A: DIRECT global->reg
// (lane(la,lg) reads row la's 32 B = exactly its MFMA A-fragment), cvt->bf16, and the
// same regs feed the fused states-copy (nt-store). NO A-LDS. B: 64 KB dbuf LDS via
// global_load_lds from L2-resident pre-swizzled wT. One s_barrier + counted vmcnt(4)
// per chunk (retires exactly the 4 B-loads; A-prefetch + store-acks stay in flight).
// LDS 64 KB + regs <=128 -> 2 independent blocks/CU (16 waves), barriers interleave.
__global__ __launch_bounds__(512, 4) void comp_gemm_kernel(
    const float* __restrict__ states,
    const unsigned short* __restrict__ wT,
    const float* __restrict__ cb1,
    const float* __restrict__ cW2,
    const float* __restrict__ cb2,
    float* __restrict__ out,
    float* __restrict__ part_ws) {
    __shared__ alignas(16) char ldsB[65536];   // B [2][512 rows][64 B]

    const int t = threadIdx.x;
    const int lane = t & 63;
    const int wv = t >> 6;        // 0..7
    const int wm = wv >> 2;       // 0..1 : rows [wm*16, +16)
    const int wn = wv & 3;        // 0..3 : cols [wn*128, +128)
    const int la = lane & 15;
    const int lg = lane >> 4;
    const int b = blockIdx.x >> 7;
    const int s0 = (blockIdx.x & 127) * 32;

    // ---- A / out per-lane pointers: row (b, s0+wm*16+la), k base lg*8 ----
    const size_t arow = ((size_t)b * S_LEN + s0 + wm * 16 + la) * H_DIM + lg * 8;
    const float* srcA = states + arow;
    float* dstO = out + arow;

    // ---- B staging: 4 x global_load_lds(16B/lane)/chunk; linear dest, swizzled src ----
    const char* srcB = (const char*)wT + (size_t)(t >> 2) * 2048 + (t & 3) * 16;
    char* dstB = ldsB + t * 16;

    // ---- B read base: row = wn*128 + fc*16 + la, slot = lg ^ ((row>>1)&3) ----
    const char* brd = ldsB + (size_t)(wn * 128 + la) * 64 + ((lg ^ ((la >> 1) & 3)) * 16);

    f4 acc[8];
#pragma unroll
    for (int fc = 0; fc < 8; ++fc) acc[fc] = f4{0.f, 0.f, 0.f, 0.f};

    auto issueB = [&](int buf_, int ck_) {
#pragma unroll
        for (int i = 0; i < 4; ++i)
            __builtin_amdgcn_global_load_lds((gvp)(srcB + (size_t)i * 128 * 2048 + ck_ * 64),
                                             (lvp)(dstB + buf_ * 32768 + i * 8192), 16, 0, 0);
    };

    // ---- prologue: A(0) -> regs, B(0) -> buf0 ----
    f4 qa0 = *(const f4*)(srcA);
    f4 qa1 = *(const f4*)(srcA + 4);
    issueB(0, 0);
    asm volatile("s_waitcnt vmcnt(0)" ::: "memory");   // one-time drain
    __builtin_amdgcn_sched_barrier(0);
    __builtin_amdgcn_s_barrier();
    __builtin_amdgcn_sched_barrier(0);

#pragma unroll 2
    for (int ck = 0; ck < 32; ++ck) {
        const int buf = ck & 1;
        f4 qn0, qn1;
        if (ck < 31) {
            issueB(buf ^ 1, ck + 1);                       // 4 glB -> other buffer
            qn0 = *(const f4*)(srcA + (ck + 1) * 32);      // A(ck+1) prefetch
            qn1 = *(const f4*)(srcA + (ck + 1) * 32 + 4);
            __builtin_amdgcn_sched_barrier(0);             // pin queue: glB x4, ldA x2 first
        }
        // cvt A(ck) -> fragment, fused copy-out (store-acks queue AFTER glB+ldA)
        bf8 af;
        af[0] = (short)f2bf(qa0.x); af[1] = (short)f2bf(qa0.y);
        af[2] = (short)f2bf(qa0.z); af[3] = (short)f2bf(qa0.w);
        af[4] = (short)f2bf(qa1.x); af[5] = (short)f2bf(qa1.y);
        af[6] = (short)f2bf(qa1.z); af[7] = (short)f2bf(qa1.w);
        __builtin_nontemporal_store(qa0, (f4*)(dstO + ck * 32));
        __builtin_nontemporal_store(qa1, (f4*)(dstO + ck * 32 + 4));
        // compute: 8 B-frag reads (2-way bank, free) + 8 MFMA
        bf8 bv[8];
#pragma unroll
        for (int fc = 0; fc < 8; ++fc)
            bv[fc] = *(const bf8*)(brd + buf * 32768 + fc * 1024);
#pragma unroll
        for (int fc = 0; fc < 8; ++fc)
            acc[fc] = __builtin_amdgcn_mfma_f32_16x16x32_bf16(af, bv[fc], acc[fc], 0, 0, 0);
        if (ck < 31) {
            // queue: [glB x4, ldA x2, st x2] -> vmcnt(4) retires exactly glB
            asm volatile("s_waitcnt vmcnt(4) lgkmcnt(0)" ::: "memory");
            __builtin_amdgcn_sched_barrier(0);
            __builtin_amdgcn_s_barrier();
            __builtin_amdgcn_sched_barrier(0);
            qa0 = qn0; qa1 = qn1;
        }
    }

    // ---- epilogue: relu + dot(cW2) + sigmoid/16 -> per-(b,s) partial ----
    float w2v[8], b1v[8];
#pragma unroll
    for (int fc = 0; fc < 8; ++fc) {
        const int d = wn * 128 + fc * 16 + la;
        w2v[fc] = cW2[d];
        b1v[fc] = cb1[d];
    }
    float* part = (float*)ldsB;   // [32 rows][4 wn] overlays buf0 (iter31 read buf1)
#pragma unroll
    for (int rg = 0; rg < 4; ++rg) {
        float p = 0.f;
#pragma unroll
        for (int fc = 0; fc < 8; ++fc)
            p += fmaxf(acc[fc][rg] + b1v[fc], 0.f) * w2v[fc];
#pragma unroll
        for (int off = 1; off < 16; off <<= 1)
            p += __shfl_xor(p, off, 64);          // sum over 16 lane-columns (n)
        if (la == 0) part[(wm * 16 + lg * 4 + rg) * 4 + wn] = p;
    }
    __syncthreads();
    if (t < 32) {
        float sum = cb2[0] + part[t * 4 + 0] + part[t * 4 + 1] + part[t * 4 + 2] + part[t * 4 + 3];
        const float sg = 1.f / (1.f + __expf(-sum));
        __builtin_nontemporal_store(sg * (1.f / 16.f), part_ws + (size_t)b * S_LEN + s0 + t);
    }
}

// comp_mean[s] = sum_b partial[b][s]; steps_used ≡ 1 (rb<=128-t can never make
// trunc(rb/(S-t+1))>=2; negative rb clips to 1); rb_final = 128-4096 = -3968.
__global__ __launch_bounds__(256) void reduce_comp(const float* __restrict__ part_ws,
                                                   float* __restrict__ out) {
    const int s = blockIdx.x * 256 + threadIdx.x;
    float sum = 0.f;
#pragma unroll
    for (int b = 0; b < B_DIM; ++b) sum += part_ws[(size_t)b * S_LEN + s];
    __builtin_nontemporal_store(sum, out + OUT_BASE + S_LEN + s);    // comp_mean
    __builtin_nontemporal_store(1.0f, out + OUT_BASE + s);           // steps_used
    if (s == 0) __builtin_nontemporal_store(-3968.0f, out + OUT_BASE + 2 * S_LEN);
}

extern "C" void kernel_launch(void* const* d_in, const int* in_sizes, int n_in,
                              void* d_out, int out_size, void* d_ws, size_t ws_size,
                              hipStream_t stream) {
    const float* states = (const float*)d_in[0];
    const float* cW1 = (const float*)d_in[5];
    const float* cb1 = (const float*)d_in[6];
    const float* cW2 = (const float*)d_in[7];
    const float* cb2 = (const float*)d_in[8];
    float* out = (float*)d_out;
    unsigned short* wT = (unsigned short*)d_ws;                 // 1 MB bf16, pre-swizzled
    float* part_ws = (float*)((char*)d_ws + (size_t)D_DIM * H_DIM * 2);  // 256 KB [16][4096]

    hipLaunchKernelGGL(prep_transpose, dim3(128), dim3(256), 0, stream, cW1, wT);
    hipLaunchKernelGGL(comp_gemm_kernel, dim3(2048), dim3(512), 0, stream,
                       states, wT, cb1, cW2, cb2, out, part_ws);
    hipLaunchKernelGGL(reduce_comp, dim3(16), dim3(256), 0, stream, part_ws, out);
}

// Round 10
// 175.884 us; speedup vs baseline: 2.2175x; 2.2175x over previous
//
#include <hip/hip_runtime.h>
#include <hip/hip_bf16.h>

typedef short bf8 __attribute__((ext_vector_type(8)));   // 8 bf16 (4 VGPRs)
typedef short bf4 __attribute__((ext_vector_type(4)));   // 4 bf16 (8 B)
typedef float f4 __attribute__((ext_vector_type(4)));
typedef const __attribute__((address_space(1))) void* gvp;
typedef __attribute__((address_space(3))) void* lvp;

#define S_LEN 4096
#define H_DIM 1024
#define D_DIM 512
#define B_DIM 16
#define OUT_BASE ((size_t)B_DIM * S_LEN * H_DIM)

// float -> bf16 bits, round-to-nearest-even
static __device__ __forceinline__ unsigned short f2bf(float f) {
    union { float f; unsigned int u; } c; c.f = f;
    unsigned int u = c.u;
    return (unsigned short)((u + 0x7FFFu + ((u >> 16) & 1u)) >> 16);
}

// cW1 [K=1024][N=512] f32 -> wT[n][chunk 0..31][slot 0..3] bf16 (pitch 2048 B),
// PRE-SWIZZLED: slot sl holds k-slot j = sl ^ ((n>>1)&3). GEMM's linear global_load_lds
// + swizzled ds_read (slot = lg ^ ((la>>1)&3)) recovers k-slot lg; 2-way-bank (free).
__global__ __launch_bounds__(256) void prep_transpose(const float* __restrict__ cW1,
                                                      unsigned short* __restrict__ wT) {
    __shared__ float tile[64][68];
    const int kt = blockIdx.x >> 3;   // 16 tiles of 64 k
    const int nt = blockIdx.x & 7;    // 8 tiles of 64 n
    const int tr = threadIdx.x >> 4;
    const int tc = threadIdx.x & 15;
#pragma unroll
    for (int i = 0; i < 4; ++i) {
        const f4 v = *(const f4*)(cW1 + (size_t)(kt * 64 + i * 16 + tr) * D_DIM + nt * 64 + tc * 4);
        tile[i * 16 + tr][tc * 4 + 0] = v.x;
        tile[i * 16 + tr][tc * 4 + 1] = v.y;
        tile[i * 16 + tr][tc * 4 + 2] = v.z;
        tile[i * 16 + tr][tc * 4 + 3] = v.w;
    }
    __syncthreads();
    const int n_local = threadIdx.x & 63;
    const int q = threadIdx.x >> 6;        // slot 0..3
    const int n = nt * 64 + n_local;
    const int j = q ^ ((n >> 1) & 3);      // data k-slot stored at slot q
    char* wTb = (char*)wT;
#pragma unroll
    for (int c_local = 0; c_local < 2; ++c_local) {   // two 32-k chunks per 64k tile
        const int k0 = c_local * 32 + j * 8;
        bf8 pk;
#pragma unroll
        for (int i = 0; i < 8; ++i) pk[i] = (short)f2bf(tile[k0 + i][n_local]);
        *(bf8*)(wTb + (size_t)n * 2048 + (kt * 2 + c_local) * 64 + q * 16) = pk;
    }
}

// Mixed-block kernel: bid%3==2 -> streaming copy block; else GEMM block.
// GEMM: M=64 (one b, 64 s) x N=512, BK=32 (32 chunks), 8 waves (1M x 8N), wave 64x64,
// acc[4][4]=64 AGPR; total regs <=128 (launch_bounds 512,4) -> 2 blocks/CU co-resident.
// A: reg depth-2 prefetch -> swizzled ds_write (8 KB dbuf). B: global_load_lds from
// L2-resident pre-swizzled wT (64 KB dbuf). One s_barrier + counted vmcnt(1) per chunk.
// Copy: fully-coalesced f4 stream, 8 loads in flight, nt-stores (proven R7/R8 fast).
__global__ __launch_bounds__(512, 4) void fused_kernel(
    const float* __restrict__ states,
    const unsigned short* __restrict__ wT,
    const float* __restrict__ cb1,
    const float* __restrict__ cW2,
    const float* __restrict__ cb2,
    float* __restrict__ out,
    float* __restrict__ part_ws) {
    __shared__ alignas(16) char lds[73728];   // B [2][512][64] @0, A [2][64][64] @65536

    const int bid = blockIdx.x;
    const int r3 = bid % 3;
    const int g3 = bid / 3;
    const int t = threadIdx.x;

    if (r3 == 2) {
        // ---- copy block: contiguous 512 KB slab, read f4 / nt-store f4 ----
        const size_t off = (size_t)g3 * 131072 + t * 4;
        const float* sp = states + off;
        float* op = out + off;
#pragma unroll 1
        for (int o = 0; o < 8; ++o) {
            f4 v[8];
#pragma unroll
            for (int j = 0; j < 8; ++j)
                v[j] = *(const f4*)(sp + (size_t)(o * 8 + j) * 2048);
#pragma unroll
            for (int j = 0; j < 8; ++j)
                __builtin_nontemporal_store(v[j], (f4*)(op + (size_t)(o * 8 + j) * 2048));
        }
        return;
    }

    // ---- GEMM block ----
    const int gid = g3 * 2 + r3;          // 0..1023
    const int lane = t & 63;
    const int wv = t >> 6;                // 0..7 : n-slice [wv*64, +64)
    const int la = lane & 15;
    const int lg = lane >> 4;
    const int b = gid >> 6;
    const int s0 = (gid & 63) * 64;

    char* ldsB = lds;                     // [2][512 rows][64 B]
    char* ldsA = lds + 65536;             // [2][64 rows][64 B]

    // B staging: 4 x global_load_lds(16B/lane)/chunk; linear dest, pre-swizzled src
    const char* srcB = (const char*)wT + (size_t)(t >> 2) * 2048 + (t & 3) * 16;
    char* dstB = ldsB + t * 16;
    // B read: row = wv*64 + fc*16 + la, slot = lg ^ ((la>>1)&3)  (2-way, free)
    const char* brd = ldsB + (wv * 64 + la) * 64 + ((lg ^ ((la >> 1) & 3)) * 16);

    // A staging: thread -> (row = t>>3, kq = t&7); f4 load -> bf4 ds_write_b64
    const int arow = t >> 3;
    const int kq = t & 7;
    const float* srcA = states + ((size_t)b * S_LEN + s0 + arow) * H_DIM + kq * 4;
    char* dstA = ldsA + arow * 64 + ((((kq >> 1) ^ ((arow >> 2) & 3)) * 2 + (kq & 1)) * 8);
    // A read: row = fr*16 + la, slot = lg ^ (la>>2)  (2-way, free)
    const char* ard = ldsA + la * 64 + ((lg ^ (la >> 2)) * 16);

    f4 acc[4][4];
#pragma unroll
    for (int a = 0; a < 4; ++a)
#pragma unroll
        for (int c = 0; c < 4; ++c) acc[a][c] = f4{0.f, 0.f, 0.f, 0.f};

    auto issueB = [&](int buf_, int ck_) {
#pragma unroll
        for (int i = 0; i < 4; ++i)
            __builtin_amdgcn_global_load_lds((gvp)(srcB + (size_t)i * 128 * 2048 + ck_ * 64),
                                             (lvp)(dstB + buf_ * 32768 + i * 8192), 16, 0, 0);
    };
    auto writeA = [&](int buf_, const f4 a) {
        bf4 p;
        p[0] = (short)f2bf(a.x); p[1] = (short)f2bf(a.y);
        p[2] = (short)f2bf(a.z); p[3] = (short)f2bf(a.w);
        *(bf4*)(dstA + buf_ * 4096) = p;
    };

    // ---- prologue: A(0)+B(0) -> buf0; A(1) in regs ----
    f4 qa = *(const f4*)(srcA);
    issueB(0, 0);
    f4 qn = *(const f4*)(srcA + 32);
    writeA(0, qa);                                       // auto-waits qa only
    asm volatile("s_waitcnt vmcnt(1) lgkmcnt(0)" ::: "memory");  // B(0) landed; A(1) flying
    __builtin_amdgcn_sched_barrier(0);
    __builtin_amdgcn_s_barrier();
    __builtin_amdgcn_sched_barrier(0);
    qa = qn;

#pragma unroll 1
    for (int ck = 0; ck < 32; ++ck) {
        const int buf = ck & 1;
        if (ck < 31) {
            writeA(buf ^ 1, qa);                         // stage A(ck+1)
            issueB(buf ^ 1, ck + 1);                     // 4 glds -> other buffer
            if (ck < 30) qn = *(const f4*)(srcA + (ck + 2) * 32);   // A(ck+2) prefetch
            __builtin_amdgcn_sched_barrier(0);
        }
        // compute chunk ck from buf
        bf8 af[4];
#pragma unroll
        for (int fr = 0; fr < 4; ++fr)
            af[fr] = *(const bf8*)(ard + buf * 4096 + fr * 1024);
#pragma unroll
        for (int fc = 0; fc < 4; ++fc) {
            const bf8 bv = *(const bf8*)(brd + buf * 32768 + fc * 1024);
#pragma unroll
            for (int fr = 0; fr < 4; ++fr)
                acc[fr][fc] = __builtin_amdgcn_mfma_f32_16x16x32_bf16(af[fr], bv, acc[fr][fc], 0, 0, 0);
        }
        if (ck < 31) {
            if (ck < 30) { asm volatile("s_waitcnt vmcnt(1) lgkmcnt(0)" ::: "memory"); }
            else         { asm volatile("s_waitcnt vmcnt(0) lgkmcnt(0)" ::: "memory"); }
            __builtin_amdgcn_sched_barrier(0);
            __builtin_amdgcn_s_barrier();
            __builtin_amdgcn_sched_barrier(0);
            if (ck < 30) qa = qn;
        }
    }

    // ---- epilogue: relu + dot(cW2) + sigmoid/16 -> per-(b,s) partial ----
    float w2v[4], b1v[4];
#pragma unroll
    for (int fc = 0; fc < 4; ++fc) {
        const int d = wv * 64 + fc * 16 + la;
        w2v[fc] = cW2[d];
        b1v[fc] = cb1[d];
    }
    float* part = (float*)ldsA;   // [64 rows][8 wv] overlays A-buf0 (dead since ck30 barrier)
#pragma unroll
    for (int fr = 0; fr < 4; ++fr) {
#pragma unroll
        for (int rg = 0; rg < 4; ++rg) {
            float p = 0.f;
#pragma unroll
            for (int fc = 0; fc < 4; ++fc)
                p += fmaxf(acc[fr][fc][rg] + b1v[fc], 0.f) * w2v[fc];
#pragma unroll
            for (int off = 1; off < 16; off <<= 1)
                p += __shfl_xor(p, off, 64);      // sum over 16 lane-columns (n)
            if (la == 0) part[(fr * 16 + lg * 4 + rg) * 8 + wv] = p;
        }
    }
    __syncthreads();
    if (t < 64) {
        float sum = cb2[0];
#pragma unroll
        for (int ww = 0; ww < 8; ++ww) sum += part[t * 8 + ww];
        const float sg = 1.f / (1.f + __expf(-sum));
        __builtin_nontemporal_store(sg * (1.f / 16.f), part_ws + (size_t)b * S_LEN + s0 + t);
    }
}

// comp_mean[s] = sum_b partial[b][s]; steps_used ≡ 1 (rb<=128-t can never make
// trunc(rb/(S-t+1))>=2; negative rb clips to 1); rb_final = 128-4096 = -3968.
__global__ __launch_bounds__(256) void reduce_comp(const float* __restrict__ part_ws,
                                                   float* __restrict__ out) {
    const int s = blockIdx.x * 256 + threadIdx.x;
    float sum = 0.f;
#pragma unroll
    for (int b = 0; b < B_DIM; ++b) sum += part_ws[(size_t)b * S_LEN + s];
    __builtin_nontemporal_store(sum, out + OUT_BASE + S_LEN + s);    // comp_mean
    __builtin_nontemporal_store(1.0f, out + OUT_BASE + s);           // steps_used
    if (s == 0) __builtin_nontemporal_store(-3968.0f, out + OUT_BASE + 2 * S_LEN);
}

extern "C" void kernel_launch(void* const* d_in, const int* in_sizes, int n_in,
                              void* d_out, int out_size, void* d_ws, size_t ws_size,
                              hipStream_t stream) {
    const float* states = (const float*)d_in[0];
    const float* cW1 = (const float*)d_in[5];
    const float* cb1 = (const float*)d_in[6];
    const float* cW2 = (const float*)d_in[7];
    const float* cb2 = (const float*)d_in[8];
    float* out = (float*)d_out;
    unsigned short* wT = (unsigned short*)d_ws;                 // 1 MB bf16, pre-swizzled
    float* part_ws = (float*)((char*)d_ws + (size_t)D_DIM * H_DIM * 2);  // 256 KB [16][4096]

    hipLaunchKernelGGL(prep_transpose, dim3(128), dim3(256), 0, stream, cW1, wT);
    hipLaunchKernelGGL(fused_kernel, dim3(1536), dim3(512), 0, stream,
                       states, wT, cb1, cW2, cb2, out, part_ws);
    hipLaunchKernelGGL(reduce_comp, dim3(16), dim3(256), 0, stream, part_ws, out);
}